// Round 4
// baseline (157.135 us; speedup 1.0000x reference)
//
#include <hip/hip_runtime.h>

#define NPTS 320
#define NCHUNK 8
#define PIX_PER_BLOCK 64
#define D0 2.0f
#define DSTEP (4.0f / 319.0f)
#define HALFV (765.0f / 512.0f)  // (3/256)*255*0.5
#define DENSITY_C 0.1f

// ---------------------------------------------------------------------------
// Kernel 1: ray-march. Block = 512 threads = 8 waves. lane (0..63) = pixel,
// wave (0..7) = depth chunk. ROUND-5 CHANGE (re-submitted; round-3 bench was
// an infra failure): per-ray BALANCED chunk split.
//   Previously chunk c was the fixed p-range [40c, 40c+40); chunks outside
//   the ray's active slab interval idled at the barrier (VALUBusy ~33%,
//   6/8..1/8 waves busy depending on ray). Now each ray divides ITS OWN
//   active interval [i_out_lo, i_out_hi) evenly: chunk c = [lo + n*c/8,
//   lo + n*(c+1)/8). Segmented compositing (per-chunk acc/T + ordered LDS
//   combine) is unchanged, so this is exact. Every wave now does ~n/8
//   samples -> intra-block wave idling eliminated.
// ---------------------------------------------------------------------------
__global__ __launch_bounds__(512, 6)
void render_kernel(const float* __restrict__ vol,
                   const float* __restrict__ R,
                   const float* __restrict__ T,
                   float* __restrict__ raw,
                   float* __restrict__ bsum,
                   float* __restrict__ bsumsq,
                   float* __restrict__ bmin,
                   float* __restrict__ bmax) {
  const int lane  = threadIdx.x & 63;
  const int chunk = threadIdx.x >> 6;
  const int pixel = blockIdx.x * PIX_PER_BLOCK + lane;
  const int h = pixel >> 8;
  const int w = pixel & 255;

  // camera-plane coords / FOCAL(=2)
  const float xh = (w * (2.0f / 255.0f) - 1.0f) * 0.5f;
  const float yh = (h * (2.0f / 255.0f) - 1.0f) * 0.5f;

  const float R00 = R[0], R01 = R[1], R02 = R[2];
  const float R10 = R[3], R11 = R[4], R12 = R[5];
  const float R20 = R[6], R21 = R[7], R22 = R[8];
  const float T0 = T[0], T1 = T[1], T2 = T[2];

  // pw = R * (pcam - T); pcam = (xh*d, yh*d, d) -> voxel coords LINEAR in d.
  const float S = 127.5f / HALFV;
  const float Cx = R00 * xh + R01 * yh + R02;
  const float Cy = R10 * xh + R11 * yh + R12;
  const float Cz = R20 * xh + R21 * yh + R22;
  const float Kx = -(R00 * T0 + R01 * T1 + R02 * T2);
  const float Ky = -(R10 * T0 + R11 * T1 + R12 * T2);
  const float Kz = -(R20 * T0 + R21 * T1 + R22 * T2);
  const float ax = Cx * S, bx = Kx * S + 127.5f;
  const float ay = Cy * S, by = Ky * S + 127.5f;
  const float az = Cz * S, bz = Kz * S + 127.5f;
  // ix(p) = ix0 + p*dix with d = D0 + p*DSTEP
  const float ix0 = ax * D0 + bx, dix = ax * DSTEP;
  const float iy0 = ay * D0 + by, diy = ay * DSTEP;
  const float iz0 = az * D0 + bz, diz = az * DSTEP;

  // --- slab intervals in p-space -------------------------------------------
  float plo_in = -1e9f, phi_in = 1e9f, plo_out = -1e9f, phi_out = 1e9f;
  auto slab = [](float a, float b, float L, float H, float& lo, float& hi) {
    if (fabsf(a) < 1e-5f) {           // drift over 320 steps < 0.0032 < margin
      if (b < L || b > H) { lo = 1e9f; hi = -1e9f; }
    } else {
      const float p1 = (L - b) / a, p2 = (H - b) / a;
      lo = fmaxf(lo, fminf(p1, p2));
      hi = fminf(hi, fmaxf(p1, p2));
    }
  };
  slab(dix, ix0, 0.01f, 254.99f, plo_in, phi_in);
  slab(diy, iy0, 0.01f, 254.99f, plo_in, phi_in);
  slab(diz, iz0, 0.01f, 254.99f, plo_in, phi_in);
  slab(dix, ix0, -1.01f, 256.01f, plo_out, phi_out);
  slab(diy, iy0, -1.01f, 256.01f, plo_out, phi_out);
  slab(diz, iz0, -1.01f, 256.01f, plo_out, phi_out);

  const int i_in_lo  = (int)ceilf(fminf(fmaxf(plo_in, 0.0f), 320.0f));
  const int i_in_hi  = (int)floorf(fminf(fmaxf(phi_in, -1.0f), 319.0f)) + 1;
  const int i_out_lo = (int)ceilf(fminf(fmaxf(plo_out, 0.0f), 320.0f));
  const int i_out_hi = (int)floorf(fminf(fmaxf(phi_out, -1.0f), 319.0f)) + 1;

  // ---- balanced per-ray chunk bounds (n_act <= 321, no overflow) ----------
  const int n_act = max(0, i_out_hi - i_out_lo);
  const int c_lo  = i_out_lo + ((n_act * chunk) >> 3);
  const int c_hi  = i_out_lo + ((n_act * (chunk + 1)) >> 3);

  float acc = 0.0f;   // chunk-local composited rgb
  float Tac = 1.0f;   // chunk-local transmittance

  // exact (clamped + masked) sample
  auto masked_sample = [&](int p) {
    const float pf = (float)p;
    const float ix = fmaf(pf, dix, ix0);
    const float iy = fmaf(pf, diy, iy0);
    const float iz = fmaf(pf, diz, iz0);
    if (ix > -1.0f && ix < 256.0f && iy > -1.0f && iy < 256.0f &&
        iz > -1.0f && iz < 256.0f) {
      const float xf = floorf(ix), yf = floorf(iy), zf = floorf(iz);
      const float fx = ix - xf, fy = iy - yf, fz = iz - zf;
      const int x0 = (int)xf, y0 = (int)yf, z0 = (int)zf;
      const float wx0 = (x0 >= 0)   ? 1.0f - fx : 0.0f;
      const float wx1 = (x0 <= 254) ? fx        : 0.0f;
      const float wy0 = (y0 >= 0)   ? 1.0f - fy : 0.0f;
      const float wy1 = (y0 <= 254) ? fy        : 0.0f;
      const float wz0 = (z0 >= 0)   ? 1.0f - fz : 0.0f;
      const float wz1 = (z0 <= 254) ? fz        : 0.0f;
      const int xc0 = max(x0, 0),     xc1 = min(x0 + 1, 255);
      const int yc0 = max(y0, 0),     yc1 = min(y0 + 1, 255);
      const int zc0 = max(z0, 0),     zc1 = min(z0 + 1, 255);
      const int b00 = (zc0 * 256 + yc0) * 256;
      const int b01 = (zc0 * 256 + yc1) * 256;
      const int b10 = (zc1 * 256 + yc0) * 256;
      const int b11 = (zc1 * 256 + yc1) * 256;
      const float v000 = vol[b00 + xc0], v001 = vol[b00 + xc1];
      const float v010 = vol[b01 + xc0], v011 = vol[b01 + xc1];
      const float v100 = vol[b10 + xc0], v101 = vol[b10 + xc1];
      const float v110 = vol[b11 + xc0], v111 = vol[b11 + xc1];
      const float fs =
          wz0 * (wy0 * (wx0 * v000 + wx1 * v001) +
                 wy1 * (wx0 * v010 + wx1 * v011)) +
          wz1 * (wy0 * (wx0 * v100 + wx1 * v101) +
                 wy1 * (wx0 * v110 + wx1 * v111));
      const float wsum  = (wx0 + wx1) * (wy0 + wy1) * (wz0 + wz1);
      const float sigma = DENSITY_C * wsum;
      acc = fmaf(sigma * Tac, fs, acc);
      Tac *= (1.0f + 1e-10f - sigma);
    } else {
      Tac *= (1.0f + 1e-10f);
    }
  };

  // interior trilinear sample (no clamps/masks; x0,y0,z0 in [0,254]).
  // 4 float2 loads of the x-contiguous corner pairs. base+65793 < 256^3.
  auto fast_sample = [&](int p) -> float {
    const float pf = (float)p;
    const float ix = fmaf(pf, dix, ix0);
    const float iy = fmaf(pf, diy, iy0);
    const float iz = fmaf(pf, diz, iz0);
    const int x0 = (int)ix, y0 = (int)iy, z0 = (int)iz;  // >=0: trunc==floor
    const float fx = ix - (float)x0;
    const float fy = iy - (float)y0;
    const float fz = iz - (float)z0;
    const int base = (z0 << 16) + (y0 << 8) + x0;
    const float2 va = *reinterpret_cast<const float2*>(vol + base);          // (v000,v001)
    const float2 vb = *reinterpret_cast<const float2*>(vol + base + 256);    // (v010,v011)
    const float2 vc = *reinterpret_cast<const float2*>(vol + base + 65536);  // (v100,v101)
    const float2 vd = *reinterpret_cast<const float2*>(vol + base + 65792);  // (v110,v111)
    const float c00 = fmaf(fx, va.y - va.x, va.x);
    const float c01 = fmaf(fx, vb.y - vb.x, vb.x);
    const float c10 = fmaf(fx, vc.y - vc.x, vc.x);
    const float c11 = fmaf(fx, vd.y - vd.x, vd.x);
    const float c0  = fmaf(fy, c01 - c00, c00);
    const float c1  = fmaf(fy, c11 - c10, c10);
    return fmaf(fz, c1 - c0, c0);
  };

  // partition [c_lo, c_hi) into masked | fast | masked
  const int lo_f = min(max(c_lo, i_in_lo), c_hi);
  const int hi_f = min(max(lo_f, i_in_hi), c_hi);

  for (int p = c_lo; p < lo_f; ++p) masked_sample(p);

  // groups of 4: recurrence regrouped (sigma == 0.1, t == 0.9 in interior);
  // all 16 float2 loads + 4 lerp trees per group are independent.
  int p = lo_f;
#pragma unroll 1
  for (; p + 4 <= hi_f; p += 4) {
    const float fs0 = fast_sample(p);
    const float fs1 = fast_sample(p + 1);
    const float fs2 = fast_sample(p + 2);
    const float fs3 = fast_sample(p + 3);
    const float g = fmaf(0.729f, fs3,
                    fmaf(0.81f,  fs2,
                    fmaf(0.9f,   fs1, fs0)));
    acc = fmaf(Tac * DENSITY_C, g, acc);
    Tac *= 0.6561f;   // 0.9^4
  }
  for (; p < hi_f; ++p) {
    const float fs = fast_sample(p);
    acc = fmaf(Tac * DENSITY_C, fs, acc);
    Tac *= (1.0f - DENSITY_C);
  }

  for (p = hi_f; p < c_hi; ++p) masked_sample(p);

  __shared__ float lrgb[NCHUNK][PIX_PER_BLOCK];
  __shared__ float lT[NCHUNK][PIX_PER_BLOCK];
  lrgb[chunk][lane] = acc;
  lT[chunk][lane]   = Tac;
  __syncthreads();

  if (threadIdx.x < 64) {
    float a = 0.0f, Tp = 1.0f;
#pragma unroll
    for (int c = 0; c < NCHUNK; ++c) {
      a  = fmaf(Tp, lrgb[c][lane], a);
      Tp *= lT[c][lane];
    }
    raw[pixel] = a;

    float s = a, q = a * a, mn = a, mx = a;
#pragma unroll
    for (int off = 32; off > 0; off >>= 1) {
      s += __shfl_down(s, off, 64);
      q += __shfl_down(q, off, 64);
      mn = fminf(mn, __shfl_down(mn, off, 64));
      mx = fmaxf(mx, __shfl_down(mx, off, 64));
    }
    if (lane == 0) {
      bsum[blockIdx.x]   = s;
      bsumsq[blockIdx.x] = q;
      bmin[blockIdx.x]   = mn;
      bmax[blockIdx.x]   = mx;
    }
  }
}

// ---------------------------------------------------------------------------
// Kernel 2: fused stats + normalize + transpose (1024 partials).
// ---------------------------------------------------------------------------
__global__ __launch_bounds__(1024)
void finalize_kernel(const float* __restrict__ raw,
                     const float* __restrict__ bsum,
                     const float* __restrict__ bsumsq,
                     const float* __restrict__ bmin,
                     const float* __restrict__ bmax,
                     float* __restrict__ out) {
  __shared__ double sS[1024];
  __shared__ double sQ[1024];
  __shared__ float sMn[1024], sMx[1024];
  const int t = threadIdx.x;
  sS[t] = (double)bsum[t];
  sQ[t] = (double)bsumsq[t];
  sMn[t] = bmin[t];
  sMx[t] = bmax[t];
  __syncthreads();
  for (int off = 512; off > 0; off >>= 1) {
    if (t < off) {
      sS[t] += sS[t + off];
      sQ[t] += sQ[t + off];
      sMn[t] = fminf(sMn[t], sMn[t + off]);
      sMx[t] = fmaxf(sMx[t], sMx[t + off]);
    }
    __syncthreads();
  }
  const double N = 65536.0;
  const double sum = sS[0], sumsq = sQ[0];
  const double mean = sum / N;
  double var = (sumsq - sum * sum / N) / (N - 1.0);
  if (var < 0.0) var = 0.0;
  const float stdeps = (float)sqrt(var) + 1e-8f;
  const float inv_std = 1.0f / stdeps;
  const float fmean = (float)mean;
  const float smin = (sMn[0] - fmean) * inv_std;
  const float smax = (sMx[0] - fmean) * inv_std;
  const float inv_range = 1.0f / (smax - smin + 1e-8f);

  const int o = blockIdx.x * 1024 + t;
  const int wq = o >> 8;    // output row (W index)
  const int hq = o & 255;   // output col (H index)
  const float s = (raw[hq * 256 + wq] - fmean) * inv_std;
  out[o] = (s - smin + 1e-8f) * inv_range;
}

extern "C" void kernel_launch(void* const* d_in, const int* in_sizes, int n_in,
                              void* d_out, int out_size, void* d_ws, size_t ws_size,
                              hipStream_t stream) {
  const float* vol = (const float*)d_in[0];  // (256,256,256) fp32
  const float* R   = (const float*)d_in[1];  // (1,3,3)
  const float* T   = (const float*)d_in[2];  // (1,3)
  float* out = (float*)d_out;                // 65536 fp32

  float* raw    = (float*)d_ws;              // 65536
  float* bsum   = raw + 65536;               // 1024
  float* bsumsq = bsum + 1024;               // 1024
  float* bmin   = bsumsq + 1024;             // 1024
  float* bmax   = bmin + 1024;               // 1024

  render_kernel<<<1024, 512, 0, stream>>>(vol, R, T, raw, bsum, bsumsq, bmin, bmax);
  finalize_kernel<<<64, 1024, 0, stream>>>(raw, bsum, bsumsq, bmin, bmax, out);
}

// Round 5
// 121.628 us; speedup vs baseline: 1.2919x; 1.2919x over previous
//
#include <hip/hip_runtime.h>

#define NPTS 320
#define NCHUNK 8
#define CHUNK (NPTS / NCHUNK)   // 40
#define PIX_PER_BLOCK 64
#define D0 2.0f
#define DSTEP (4.0f / 319.0f)
#define HALFV (765.0f / 512.0f)  // (3/256)*255*0.5
#define DENSITY_C 0.1f
// 0.9^132 = 9.4e-7: a chunk whose upstream interior path has >=132 steps
// contributes < 1e-6 to raw (feat<=1, sum(weights) <= T_upstream).
#define SKIP_STEPS 132

// ---------------------------------------------------------------------------
// Kernel 1: ray-march. Block = 512 threads = 8 waves. lane (0..63) = pixel,
// wave (0..7) = FIXED depth chunk [40c, 40c+40)  (wave-uniform bounds; the
// round-4 per-ray balanced split made bounds per-LANE, scattering each
// wave-gather across disjoint depth regions -> ~3x cache lines/load, -70%).
// ROUND-5 CHANGE: transmittance-bound chunk skip. Interior steps multiply
// T by exactly 0.9 (wsum==1, independent of volume data), so a chunk with
// u = min(p0, i_in_hi) - i_in_lo >= 132 upstream interior steps has
// T_upstream <= 0.9^132 < 1e-6 and its whole contribution is below 1e-6
// in raw (~5e-6 after normalization, tolerance 3.9e-3). Skipped waves
// store (acc=0, T=1) -> ordered LDS combine unchanged. This removes the
// deep-chunk work of exactly the heaviest (central) blocks, cutting the
// per-CU contended gather traffic ~30%.
// ---------------------------------------------------------------------------
__global__ __launch_bounds__(512, 6)
void render_kernel(const float* __restrict__ vol,
                   const float* __restrict__ R,
                   const float* __restrict__ T,
                   float* __restrict__ raw,
                   float* __restrict__ bsum,
                   float* __restrict__ bsumsq,
                   float* __restrict__ bmin,
                   float* __restrict__ bmax) {
  const int lane  = threadIdx.x & 63;
  const int chunk = threadIdx.x >> 6;
  const int pixel = blockIdx.x * PIX_PER_BLOCK + lane;
  const int h = pixel >> 8;
  const int w = pixel & 255;

  // camera-plane coords / FOCAL(=2)
  const float xh = (w * (2.0f / 255.0f) - 1.0f) * 0.5f;
  const float yh = (h * (2.0f / 255.0f) - 1.0f) * 0.5f;

  const float R00 = R[0], R01 = R[1], R02 = R[2];
  const float R10 = R[3], R11 = R[4], R12 = R[5];
  const float R20 = R[6], R21 = R[7], R22 = R[8];
  const float T0 = T[0], T1 = T[1], T2 = T[2];

  // pw = R * (pcam - T); pcam = (xh*d, yh*d, d) -> voxel coords LINEAR in d.
  const float S = 127.5f / HALFV;
  const float Cx = R00 * xh + R01 * yh + R02;
  const float Cy = R10 * xh + R11 * yh + R12;
  const float Cz = R20 * xh + R21 * yh + R22;
  const float Kx = -(R00 * T0 + R01 * T1 + R02 * T2);
  const float Ky = -(R10 * T0 + R11 * T1 + R12 * T2);
  const float Kz = -(R20 * T0 + R21 * T1 + R22 * T2);
  const float ax = Cx * S, bx = Kx * S + 127.5f;
  const float ay = Cy * S, by = Ky * S + 127.5f;
  const float az = Cz * S, bz = Kz * S + 127.5f;
  // ix(p) = ix0 + p*dix with d = D0 + p*DSTEP
  const float ix0 = ax * D0 + bx, dix = ax * DSTEP;
  const float iy0 = ay * D0 + by, diy = ay * DSTEP;
  const float iz0 = az * D0 + bz, diz = az * DSTEP;

  // --- slab intervals in p-space -------------------------------------------
  float plo_in = -1e9f, phi_in = 1e9f, plo_out = -1e9f, phi_out = 1e9f;
  auto slab = [](float a, float b, float L, float H, float& lo, float& hi) {
    if (fabsf(a) < 1e-5f) {           // drift over 320 steps < 0.0032 < margin
      if (b < L || b > H) { lo = 1e9f; hi = -1e9f; }
    } else {
      const float p1 = (L - b) / a, p2 = (H - b) / a;
      lo = fmaxf(lo, fminf(p1, p2));
      hi = fminf(hi, fmaxf(p1, p2));
    }
  };
  slab(dix, ix0, 0.01f, 254.99f, plo_in, phi_in);
  slab(diy, iy0, 0.01f, 254.99f, plo_in, phi_in);
  slab(diz, iz0, 0.01f, 254.99f, plo_in, phi_in);
  slab(dix, ix0, -1.01f, 256.01f, plo_out, phi_out);
  slab(diy, iy0, -1.01f, 256.01f, plo_out, phi_out);
  slab(diz, iz0, -1.01f, 256.01f, plo_out, phi_out);

  const int i_in_lo  = (int)ceilf(fminf(fmaxf(plo_in, 0.0f), 320.0f));
  const int i_in_hi  = (int)floorf(fminf(fmaxf(phi_in, -1.0f), 319.0f)) + 1;
  const int i_out_lo = (int)ceilf(fminf(fmaxf(plo_out, 0.0f), 320.0f));
  const int i_out_hi = (int)floorf(fminf(fmaxf(phi_out, -1.0f), 319.0f)) + 1;

  float acc = 0.0f;   // chunk-local composited rgb
  float Tac = 1.0f;   // chunk-local transmittance
  const int p0 = chunk * CHUNK;

  // Transmittance bound: upstream interior steps (each multiplies T by 0.9
  // exactly; boundary steps only shrink T further).
  const int u_int = min(p0, i_in_hi) - i_in_lo;
  if (u_int < SKIP_STEPS) {

    // exact (clamped + masked) sample
    auto masked_sample = [&](int p) {
      const float pf = (float)p;
      const float ix = fmaf(pf, dix, ix0);
      const float iy = fmaf(pf, diy, iy0);
      const float iz = fmaf(pf, diz, iz0);
      if (ix > -1.0f && ix < 256.0f && iy > -1.0f && iy < 256.0f &&
          iz > -1.0f && iz < 256.0f) {
        const float xf = floorf(ix), yf = floorf(iy), zf = floorf(iz);
        const float fx = ix - xf, fy = iy - yf, fz = iz - zf;
        const int x0 = (int)xf, y0 = (int)yf, z0 = (int)zf;
        const float wx0 = (x0 >= 0)   ? 1.0f - fx : 0.0f;
        const float wx1 = (x0 <= 254) ? fx        : 0.0f;
        const float wy0 = (y0 >= 0)   ? 1.0f - fy : 0.0f;
        const float wy1 = (y0 <= 254) ? fy        : 0.0f;
        const float wz0 = (z0 >= 0)   ? 1.0f - fz : 0.0f;
        const float wz1 = (z0 <= 254) ? fz        : 0.0f;
        const int xc0 = max(x0, 0),     xc1 = min(x0 + 1, 255);
        const int yc0 = max(y0, 0),     yc1 = min(y0 + 1, 255);
        const int zc0 = max(z0, 0),     zc1 = min(z0 + 1, 255);
        const int b00 = (zc0 * 256 + yc0) * 256;
        const int b01 = (zc0 * 256 + yc1) * 256;
        const int b10 = (zc1 * 256 + yc0) * 256;
        const int b11 = (zc1 * 256 + yc1) * 256;
        const float v000 = vol[b00 + xc0], v001 = vol[b00 + xc1];
        const float v010 = vol[b01 + xc0], v011 = vol[b01 + xc1];
        const float v100 = vol[b10 + xc0], v101 = vol[b10 + xc1];
        const float v110 = vol[b11 + xc0], v111 = vol[b11 + xc1];
        const float fs =
            wz0 * (wy0 * (wx0 * v000 + wx1 * v001) +
                   wy1 * (wx0 * v010 + wx1 * v011)) +
            wz1 * (wy0 * (wx0 * v100 + wx1 * v101) +
                   wy1 * (wx0 * v110 + wx1 * v111));
        const float wsum  = (wx0 + wx1) * (wy0 + wy1) * (wz0 + wz1);
        const float sigma = DENSITY_C * wsum;
        acc = fmaf(sigma * Tac, fs, acc);
        Tac *= (1.0f + 1e-10f - sigma);
      } else {
        Tac *= (1.0f + 1e-10f);
      }
    };

    // interior trilinear sample (no clamps/masks; x0,y0,z0 in [0,254]).
    // 4 float2 loads of the x-contiguous corner pairs. base+65793 < 256^3.
    auto fast_sample = [&](int p) -> float {
      const float pf = (float)p;
      const float ix = fmaf(pf, dix, ix0);
      const float iy = fmaf(pf, diy, iy0);
      const float iz = fmaf(pf, diz, iz0);
      const int x0 = (int)ix, y0 = (int)iy, z0 = (int)iz;  // >=0: trunc==floor
      const float fx = ix - (float)x0;
      const float fy = iy - (float)y0;
      const float fz = iz - (float)z0;
      const int base = (z0 << 16) + (y0 << 8) + x0;
      const float2 va = *reinterpret_cast<const float2*>(vol + base);          // (v000,v001)
      const float2 vb = *reinterpret_cast<const float2*>(vol + base + 256);    // (v010,v011)
      const float2 vc = *reinterpret_cast<const float2*>(vol + base + 65536);  // (v100,v101)
      const float2 vd = *reinterpret_cast<const float2*>(vol + base + 65792);  // (v110,v111)
      const float c00 = fmaf(fx, va.y - va.x, va.x);
      const float c01 = fmaf(fx, vb.y - vb.x, vb.x);
      const float c10 = fmaf(fx, vc.y - vc.x, vc.x);
      const float c11 = fmaf(fx, vd.y - vd.x, vd.x);
      const float c0  = fmaf(fy, c01 - c00, c00);
      const float c1  = fmaf(fy, c11 - c10, c10);
      return fmaf(fz, c1 - c0, c0);
    };

    // partition [lo_o, hi_o) into masked | fast | masked
    const int lo_o = max(p0, i_out_lo);
    const int hi_o = min(p0 + CHUNK, i_out_hi);
    const int lo_f = min(max(lo_o, i_in_lo), hi_o);
    const int hi_f = min(max(lo_f, i_in_hi), hi_o);

    for (int p = lo_o; p < lo_f; ++p) masked_sample(p);

    // groups of 4: recurrence regrouped (sigma == 0.1, t == 0.9 interior);
    // all 16 float2 loads + 4 lerp trees per group are independent.
    int p = lo_f;
#pragma unroll 1
    for (; p + 4 <= hi_f; p += 4) {
      const float fs0 = fast_sample(p);
      const float fs1 = fast_sample(p + 1);
      const float fs2 = fast_sample(p + 2);
      const float fs3 = fast_sample(p + 3);
      const float g = fmaf(0.729f, fs3,
                      fmaf(0.81f,  fs2,
                      fmaf(0.9f,   fs1, fs0)));
      acc = fmaf(Tac * DENSITY_C, g, acc);
      Tac *= 0.6561f;   // 0.9^4
    }
    for (; p < hi_f; ++p) {
      const float fs = fast_sample(p);
      acc = fmaf(Tac * DENSITY_C, fs, acc);
      Tac *= (1.0f - DENSITY_C);
    }

    for (p = hi_f; p < hi_o; ++p) masked_sample(p);
  }  // else: skipped chunk, acc = 0, Tac = 1 (error < 1e-6 in raw)

  __shared__ float lrgb[NCHUNK][PIX_PER_BLOCK];
  __shared__ float lT[NCHUNK][PIX_PER_BLOCK];
  lrgb[chunk][lane] = acc;
  lT[chunk][lane]   = Tac;
  __syncthreads();

  if (threadIdx.x < 64) {
    float a = 0.0f, Tp = 1.0f;
#pragma unroll
    for (int c = 0; c < NCHUNK; ++c) {
      a  = fmaf(Tp, lrgb[c][lane], a);
      Tp *= lT[c][lane];
    }
    raw[pixel] = a;

    float s = a, q = a * a, mn = a, mx = a;
#pragma unroll
    for (int off = 32; off > 0; off >>= 1) {
      s += __shfl_down(s, off, 64);
      q += __shfl_down(q, off, 64);
      mn = fminf(mn, __shfl_down(mn, off, 64));
      mx = fmaxf(mx, __shfl_down(mx, off, 64));
    }
    if (lane == 0) {
      bsum[blockIdx.x]   = s;
      bsumsq[blockIdx.x] = q;
      bmin[blockIdx.x]   = mn;
      bmax[blockIdx.x]   = mx;
    }
  }
}

// ---------------------------------------------------------------------------
// Kernel 2: fused stats + normalize + transpose (1024 partials).
// ---------------------------------------------------------------------------
__global__ __launch_bounds__(1024)
void finalize_kernel(const float* __restrict__ raw,
                     const float* __restrict__ bsum,
                     const float* __restrict__ bsumsq,
                     const float* __restrict__ bmin,
                     const float* __restrict__ bmax,
                     float* __restrict__ out) {
  __shared__ double sS[1024];
  __shared__ double sQ[1024];
  __shared__ float sMn[1024], sMx[1024];
  const int t = threadIdx.x;
  sS[t] = (double)bsum[t];
  sQ[t] = (double)bsumsq[t];
  sMn[t] = bmin[t];
  sMx[t] = bmax[t];
  __syncthreads();
  for (int off = 512; off > 0; off >>= 1) {
    if (t < off) {
      sS[t] += sS[t + off];
      sQ[t] += sQ[t + off];
      sMn[t] = fminf(sMn[t], sMn[t + off]);
      sMx[t] = fmaxf(sMx[t], sMx[t + off]);
    }
    __syncthreads();
  }
  const double N = 65536.0;
  const double sum = sS[0], sumsq = sQ[0];
  const double mean = sum / N;
  double var = (sumsq - sum * sum / N) / (N - 1.0);
  if (var < 0.0) var = 0.0;
  const float stdeps = (float)sqrt(var) + 1e-8f;
  const float inv_std = 1.0f / stdeps;
  const float fmean = (float)mean;
  const float smin = (sMn[0] - fmean) * inv_std;
  const float smax = (sMx[0] - fmean) * inv_std;
  const float inv_range = 1.0f / (smax - smin + 1e-8f);

  const int o = blockIdx.x * 1024 + t;
  const int wq = o >> 8;    // output row (W index)
  const int hq = o & 255;   // output col (H index)
  const float s = (raw[hq * 256 + wq] - fmean) * inv_std;
  out[o] = (s - smin + 1e-8f) * inv_range;
}

extern "C" void kernel_launch(void* const* d_in, const int* in_sizes, int n_in,
                              void* d_out, int out_size, void* d_ws, size_t ws_size,
                              hipStream_t stream) {
  const float* vol = (const float*)d_in[0];  // (256,256,256) fp32
  const float* R   = (const float*)d_in[1];  // (1,3,3)
  const float* T   = (const float*)d_in[2];  // (1,3)
  float* out = (float*)d_out;                // 65536 fp32

  float* raw    = (float*)d_ws;              // 65536
  float* bsum   = raw + 65536;               // 1024
  float* bsumsq = bsum + 1024;               // 1024
  float* bmin   = bsumsq + 1024;             // 1024
  float* bmax   = bmin + 1024;               // 1024

  render_kernel<<<1024, 512, 0, stream>>>(vol, R, T, raw, bsum, bsumsq, bmin, bmax);
  finalize_kernel<<<64, 1024, 0, stream>>>(raw, bsum, bsumsq, bmin, bmax, out);
}

// Round 6
// 119.883 us; speedup vs baseline: 1.3107x; 1.0146x over previous
//
#include <hip/hip_runtime.h>

#define NPTS 320
#define NCHUNK 8
#define CHUNK (NPTS / NCHUNK)   // 40
#define PIX_PER_BLOCK 64
#define D0 2.0f
#define DSTEP (4.0f / 319.0f)
#define HALFV (765.0f / 512.0f)  // (3/256)*255*0.5
#define DENSITY_C 0.1f
// 0.9^132 = 9.4e-7: a chunk whose upstream interior path has >=132 steps
// contributes < 1e-6 to raw (feat<=1, sum(weights) <= T_upstream).
#define SKIP_STEPS 132

// ---------------------------------------------------------------------------
// Kernel 1: ray-march. Block = 512 threads = 8 waves. lane (0..63) = pixel,
// wave (0..7) = FIXED depth chunk [40c, 40c+40) (wave-uniform bounds).
// ROUND-6 CHANGE: exposed-latency reduction.
//   R1 (fewer load instrs), R5 (27% less traffic) both ~neutral on time ->
//   kernel is latency-bound: each group of 4 issued 16 loads then waited
//   full memory latency (10 exposures per 40-sample chain, 40 VGPR = no
//   deeper pipelining possible). Now: GROUPS OF 8 (32 loads in flight per
//   wait, 5 exposures per chain) + __launch_bounds__(512,4) to allow ~128
//   VGPR. In-flight loads per SIMD rises 8wx16 -> 5wx32. Full interior
//   chunk = exactly 5 groups (40/8), no remainder.
// ---------------------------------------------------------------------------
__global__ __launch_bounds__(512, 4)
void render_kernel(const float* __restrict__ vol,
                   const float* __restrict__ R,
                   const float* __restrict__ T,
                   float* __restrict__ raw,
                   float* __restrict__ bsum,
                   float* __restrict__ bsumsq,
                   float* __restrict__ bmin,
                   float* __restrict__ bmax) {
  const int lane  = threadIdx.x & 63;
  const int chunk = threadIdx.x >> 6;
  const int pixel = blockIdx.x * PIX_PER_BLOCK + lane;
  const int h = pixel >> 8;
  const int w = pixel & 255;

  // camera-plane coords / FOCAL(=2)
  const float xh = (w * (2.0f / 255.0f) - 1.0f) * 0.5f;
  const float yh = (h * (2.0f / 255.0f) - 1.0f) * 0.5f;

  const float R00 = R[0], R01 = R[1], R02 = R[2];
  const float R10 = R[3], R11 = R[4], R12 = R[5];
  const float R20 = R[6], R21 = R[7], R22 = R[8];
  const float T0 = T[0], T1 = T[1], T2 = T[2];

  // pw = R * (pcam - T); pcam = (xh*d, yh*d, d) -> voxel coords LINEAR in d.
  const float S = 127.5f / HALFV;
  const float Cx = R00 * xh + R01 * yh + R02;
  const float Cy = R10 * xh + R11 * yh + R12;
  const float Cz = R20 * xh + R21 * yh + R22;
  const float Kx = -(R00 * T0 + R01 * T1 + R02 * T2);
  const float Ky = -(R10 * T0 + R11 * T1 + R12 * T2);
  const float Kz = -(R20 * T0 + R21 * T1 + R22 * T2);
  const float ax = Cx * S, bx = Kx * S + 127.5f;
  const float ay = Cy * S, by = Ky * S + 127.5f;
  const float az = Cz * S, bz = Kz * S + 127.5f;
  // ix(p) = ix0 + p*dix with d = D0 + p*DSTEP
  const float ix0 = ax * D0 + bx, dix = ax * DSTEP;
  const float iy0 = ay * D0 + by, diy = ay * DSTEP;
  const float iz0 = az * D0 + bz, diz = az * DSTEP;

  // --- slab intervals in p-space -------------------------------------------
  float plo_in = -1e9f, phi_in = 1e9f, plo_out = -1e9f, phi_out = 1e9f;
  auto slab = [](float a, float b, float L, float H, float& lo, float& hi) {
    if (fabsf(a) < 1e-5f) {           // drift over 320 steps < 0.0032 < margin
      if (b < L || b > H) { lo = 1e9f; hi = -1e9f; }
    } else {
      const float p1 = (L - b) / a, p2 = (H - b) / a;
      lo = fmaxf(lo, fminf(p1, p2));
      hi = fminf(hi, fmaxf(p1, p2));
    }
  };
  slab(dix, ix0, 0.01f, 254.99f, plo_in, phi_in);
  slab(diy, iy0, 0.01f, 254.99f, plo_in, phi_in);
  slab(diz, iz0, 0.01f, 254.99f, plo_in, phi_in);
  slab(dix, ix0, -1.01f, 256.01f, plo_out, phi_out);
  slab(diy, iy0, -1.01f, 256.01f, plo_out, phi_out);
  slab(diz, iz0, -1.01f, 256.01f, plo_out, phi_out);

  const int i_in_lo  = (int)ceilf(fminf(fmaxf(plo_in, 0.0f), 320.0f));
  const int i_in_hi  = (int)floorf(fminf(fmaxf(phi_in, -1.0f), 319.0f)) + 1;
  const int i_out_lo = (int)ceilf(fminf(fmaxf(plo_out, 0.0f), 320.0f));
  const int i_out_hi = (int)floorf(fminf(fmaxf(phi_out, -1.0f), 319.0f)) + 1;

  float acc = 0.0f;   // chunk-local composited rgb
  float Tac = 1.0f;   // chunk-local transmittance
  const int p0 = chunk * CHUNK;

  // Transmittance bound: upstream interior steps (each multiplies T by 0.9
  // exactly; boundary steps only shrink T further).
  const int u_int = min(p0, i_in_hi) - i_in_lo;
  if (u_int < SKIP_STEPS) {

    // exact (clamped + masked) sample
    auto masked_sample = [&](int p) {
      const float pf = (float)p;
      const float ix = fmaf(pf, dix, ix0);
      const float iy = fmaf(pf, diy, iy0);
      const float iz = fmaf(pf, diz, iz0);
      if (ix > -1.0f && ix < 256.0f && iy > -1.0f && iy < 256.0f &&
          iz > -1.0f && iz < 256.0f) {
        const float xf = floorf(ix), yf = floorf(iy), zf = floorf(iz);
        const float fx = ix - xf, fy = iy - yf, fz = iz - zf;
        const int x0 = (int)xf, y0 = (int)yf, z0 = (int)zf;
        const float wx0 = (x0 >= 0)   ? 1.0f - fx : 0.0f;
        const float wx1 = (x0 <= 254) ? fx        : 0.0f;
        const float wy0 = (y0 >= 0)   ? 1.0f - fy : 0.0f;
        const float wy1 = (y0 <= 254) ? fy        : 0.0f;
        const float wz0 = (z0 >= 0)   ? 1.0f - fz : 0.0f;
        const float wz1 = (z0 <= 254) ? fz        : 0.0f;
        const int xc0 = max(x0, 0),     xc1 = min(x0 + 1, 255);
        const int yc0 = max(y0, 0),     yc1 = min(y0 + 1, 255);
        const int zc0 = max(z0, 0),     zc1 = min(z0 + 1, 255);
        const int b00 = (zc0 * 256 + yc0) * 256;
        const int b01 = (zc0 * 256 + yc1) * 256;
        const int b10 = (zc1 * 256 + yc0) * 256;
        const int b11 = (zc1 * 256 + yc1) * 256;
        const float v000 = vol[b00 + xc0], v001 = vol[b00 + xc1];
        const float v010 = vol[b01 + xc0], v011 = vol[b01 + xc1];
        const float v100 = vol[b10 + xc0], v101 = vol[b10 + xc1];
        const float v110 = vol[b11 + xc0], v111 = vol[b11 + xc1];
        const float fs =
            wz0 * (wy0 * (wx0 * v000 + wx1 * v001) +
                   wy1 * (wx0 * v010 + wx1 * v011)) +
            wz1 * (wy0 * (wx0 * v100 + wx1 * v101) +
                   wy1 * (wx0 * v110 + wx1 * v111));
        const float wsum  = (wx0 + wx1) * (wy0 + wy1) * (wz0 + wz1);
        const float sigma = DENSITY_C * wsum;
        acc = fmaf(sigma * Tac, fs, acc);
        Tac *= (1.0f + 1e-10f - sigma);
      } else {
        Tac *= (1.0f + 1e-10f);
      }
    };

    // single interior trilinear sample (remainder loop)
    auto fast_sample = [&](int p) -> float {
      const float pf = (float)p;
      const float ix = fmaf(pf, dix, ix0);
      const float iy = fmaf(pf, diy, iy0);
      const float iz = fmaf(pf, diz, iz0);
      const int x0 = (int)ix, y0 = (int)iy, z0 = (int)iz;
      const float fx = ix - (float)x0;
      const float fy = iy - (float)y0;
      const float fz = iz - (float)z0;
      const int base = (z0 << 16) + (y0 << 8) + x0;
      const float* b0 = vol + base;
      const float* b1 = vol + base + 65536;
      const float2 va = *reinterpret_cast<const float2*>(b0);
      const float2 vb = *reinterpret_cast<const float2*>(b0 + 256);
      const float2 vc = *reinterpret_cast<const float2*>(b1);
      const float2 vd = *reinterpret_cast<const float2*>(b1 + 256);
      const float c00 = fmaf(fx, va.y - va.x, va.x);
      const float c01 = fmaf(fx, vb.y - vb.x, vb.x);
      const float c10 = fmaf(fx, vc.y - vc.x, vc.x);
      const float c11 = fmaf(fx, vd.y - vd.x, vd.x);
      const float c0  = fmaf(fy, c01 - c00, c00);
      const float c1  = fmaf(fy, c11 - c10, c10);
      return fmaf(fz, c1 - c0, c0);
    };

    // partition [lo_o, hi_o) into masked | fast | masked
    const int lo_o = max(p0, i_out_lo);
    const int hi_o = min(p0 + CHUNK, i_out_hi);
    const int lo_f = min(max(lo_o, i_in_lo), hi_o);
    const int hi_f = min(max(lo_f, i_in_hi), hi_o);

    for (int p = lo_o; p < lo_f; ++p) masked_sample(p);

    // groups of 8: 32 independent float2 loads in flight per wait.
    // Recurrence regrouped (sigma == 0.1, t == 0.9 exactly in interior):
    // acc += Tac*0.1*sum_k 0.9^k fs_k ; Tac *= 0.9^8.
    int p = lo_f;
#pragma unroll 1
    for (; p + 8 <= hi_f; p += 8) {
      float2 va[8], vb[8], vc[8], vd[8];
      float fx[8], fy[8], fz[8];
#pragma unroll
      for (int k = 0; k < 8; ++k) {
        const float pf = (float)(p + k);
        const float ix = fmaf(pf, dix, ix0);
        const float iy = fmaf(pf, diy, iy0);
        const float iz = fmaf(pf, diz, iz0);
        const int x0 = (int)ix, y0 = (int)iy, z0 = (int)iz;  // trunc==floor
        fx[k] = ix - (float)x0;
        fy[k] = iy - (float)y0;
        fz[k] = iz - (float)z0;
        const int base = (z0 << 16) + (y0 << 8) + x0;
        const float* b0 = vol + base;            // rows (z0,y0) / (z0,y0+1)
        const float* b1 = vol + base + 65536;    // rows (z0+1,y0)/(z0+1,y0+1)
        va[k] = *reinterpret_cast<const float2*>(b0);
        vb[k] = *reinterpret_cast<const float2*>(b0 + 256);
        vc[k] = *reinterpret_cast<const float2*>(b1);
        vd[k] = *reinterpret_cast<const float2*>(b1 + 256);
      }
      const float W8[8] = {1.0f, 0.9f, 0.81f, 0.729f,
                           0.6561f, 0.59049f, 0.531441f, 0.4782969f};
      float g = 0.0f;
#pragma unroll
      for (int k = 0; k < 8; ++k) {
        const float c00 = fmaf(fx[k], va[k].y - va[k].x, va[k].x);
        const float c01 = fmaf(fx[k], vb[k].y - vb[k].x, vb[k].x);
        const float c10 = fmaf(fx[k], vc[k].y - vc[k].x, vc[k].x);
        const float c11 = fmaf(fx[k], vd[k].y - vd[k].x, vd[k].x);
        const float c0  = fmaf(fy[k], c01 - c00, c00);
        const float c1  = fmaf(fy[k], c11 - c10, c10);
        const float fs  = fmaf(fz[k], c1 - c0, c0);
        g = fmaf(W8[k], fs, g);
      }
      acc = fmaf(Tac * DENSITY_C, g, acc);
      Tac *= 0.43046721f;   // 0.9^8
    }
    for (; p < hi_f; ++p) {
      const float fs = fast_sample(p);
      acc = fmaf(Tac * DENSITY_C, fs, acc);
      Tac *= (1.0f - DENSITY_C);
    }

    for (p = hi_f; p < hi_o; ++p) masked_sample(p);
  }  // else: skipped chunk, acc = 0, Tac = 1 (error < 1e-6 in raw)

  __shared__ float lrgb[NCHUNK][PIX_PER_BLOCK];
  __shared__ float lT[NCHUNK][PIX_PER_BLOCK];
  lrgb[chunk][lane] = acc;
  lT[chunk][lane]   = Tac;
  __syncthreads();

  if (threadIdx.x < 64) {
    float a = 0.0f, Tp = 1.0f;
#pragma unroll
    for (int c = 0; c < NCHUNK; ++c) {
      a  = fmaf(Tp, lrgb[c][lane], a);
      Tp *= lT[c][lane];
    }
    raw[pixel] = a;

    float s = a, q = a * a, mn = a, mx = a;
#pragma unroll
    for (int off = 32; off > 0; off >>= 1) {
      s += __shfl_down(s, off, 64);
      q += __shfl_down(q, off, 64);
      mn = fminf(mn, __shfl_down(mn, off, 64));
      mx = fmaxf(mx, __shfl_down(mx, off, 64));
    }
    if (lane == 0) {
      bsum[blockIdx.x]   = s;
      bsumsq[blockIdx.x] = q;
      bmin[blockIdx.x]   = mn;
      bmax[blockIdx.x]   = mx;
    }
  }
}

// ---------------------------------------------------------------------------
// Kernel 2: fused stats + normalize + transpose (1024 partials).
// ---------------------------------------------------------------------------
__global__ __launch_bounds__(1024)
void finalize_kernel(const float* __restrict__ raw,
                     const float* __restrict__ bsum,
                     const float* __restrict__ bsumsq,
                     const float* __restrict__ bmin,
                     const float* __restrict__ bmax,
                     float* __restrict__ out) {
  __shared__ double sS[1024];
  __shared__ double sQ[1024];
  __shared__ float sMn[1024], sMx[1024];
  const int t = threadIdx.x;
  sS[t] = (double)bsum[t];
  sQ[t] = (double)bsumsq[t];
  sMn[t] = bmin[t];
  sMx[t] = bmax[t];
  __syncthreads();
  for (int off = 512; off > 0; off >>= 1) {
    if (t < off) {
      sS[t] += sS[t + off];
      sQ[t] += sQ[t + off];
      sMn[t] = fminf(sMn[t], sMn[t + off]);
      sMx[t] = fmaxf(sMx[t], sMx[t + off]);
    }
    __syncthreads();
  }
  const double N = 65536.0;
  const double sum = sS[0], sumsq = sQ[0];
  const double mean = sum / N;
  double var = (sumsq - sum * sum / N) / (N - 1.0);
  if (var < 0.0) var = 0.0;
  const float stdeps = (float)sqrt(var) + 1e-8f;
  const float inv_std = 1.0f / stdeps;
  const float fmean = (float)mean;
  const float smin = (sMn[0] - fmean) * inv_std;
  const float smax = (sMx[0] - fmean) * inv_std;
  const float inv_range = 1.0f / (smax - smin + 1e-8f);

  const int o = blockIdx.x * 1024 + t;
  const int wq = o >> 8;    // output row (W index)
  const int hq = o & 255;   // output col (H index)
  const float s = (raw[hq * 256 + wq] - fmean) * inv_std;
  out[o] = (s - smin + 1e-8f) * inv_range;
}

extern "C" void kernel_launch(void* const* d_in, const int* in_sizes, int n_in,
                              void* d_out, int out_size, void* d_ws, size_t ws_size,
                              hipStream_t stream) {
  const float* vol = (const float*)d_in[0];  // (256,256,256) fp32
  const float* R   = (const float*)d_in[1];  // (1,3,3)
  const float* T   = (const float*)d_in[2];  // (1,3)
  float* out = (float*)d_out;                // 65536 fp32

  float* raw    = (float*)d_ws;              // 65536
  float* bsum   = raw + 65536;               // 1024
  float* bsumsq = bsum + 1024;               // 1024
  float* bmin   = bsumsq + 1024;             // 1024
  float* bmax   = bmin + 1024;               // 1024

  render_kernel<<<1024, 512, 0, stream>>>(vol, R, T, raw, bsum, bsumsq, bmin, bmax);
  finalize_kernel<<<64, 1024, 0, stream>>>(raw, bsum, bsumsq, bmin, bmax, out);
}

// Round 7
// 119.128 us; speedup vs baseline: 1.3190x; 1.0063x over previous
//
#include <hip/hip_runtime.h>

#define NPTS 320
#define NCHUNK 8
#define CHUNK (NPTS / NCHUNK)   // 40
#define PIX_PER_BLOCK 64
#define D0 2.0f
#define DSTEP (4.0f / 319.0f)
#define HALFV (765.0f / 512.0f)  // (3/256)*255*0.5
#define DENSITY_C 0.1f
// 0.9^132 = 9.4e-7: a chunk whose upstream interior path has >=132 steps
// contributes < 1e-6 to raw (feat<=1, sum(weights) <= T_upstream).
#define SKIP_STEPS 132

// ---------------------------------------------------------------------------
// Kernel 1: ray-march (unchanged from round 6: groups-of-8, chunk skip).
// ---------------------------------------------------------------------------
__global__ __launch_bounds__(512, 4)
void render_kernel(const float* __restrict__ vol,
                   const float* __restrict__ R,
                   const float* __restrict__ T,
                   float* __restrict__ raw,
                   float* __restrict__ bsum,
                   float* __restrict__ bsumsq,
                   float* __restrict__ bmin,
                   float* __restrict__ bmax) {
  const int lane  = threadIdx.x & 63;
  const int chunk = threadIdx.x >> 6;
  const int pixel = blockIdx.x * PIX_PER_BLOCK + lane;
  const int h = pixel >> 8;
  const int w = pixel & 255;

  // camera-plane coords / FOCAL(=2)
  const float xh = (w * (2.0f / 255.0f) - 1.0f) * 0.5f;
  const float yh = (h * (2.0f / 255.0f) - 1.0f) * 0.5f;

  const float R00 = R[0], R01 = R[1], R02 = R[2];
  const float R10 = R[3], R11 = R[4], R12 = R[5];
  const float R20 = R[6], R21 = R[7], R22 = R[8];
  const float T0 = T[0], T1 = T[1], T2 = T[2];

  // pw = R * (pcam - T); pcam = (xh*d, yh*d, d) -> voxel coords LINEAR in d.
  const float S = 127.5f / HALFV;
  const float Cx = R00 * xh + R01 * yh + R02;
  const float Cy = R10 * xh + R11 * yh + R12;
  const float Cz = R20 * xh + R21 * yh + R22;
  const float Kx = -(R00 * T0 + R01 * T1 + R02 * T2);
  const float Ky = -(R10 * T0 + R11 * T1 + R12 * T2);
  const float Kz = -(R20 * T0 + R21 * T1 + R22 * T2);
  const float ax = Cx * S, bx = Kx * S + 127.5f;
  const float ay = Cy * S, by = Ky * S + 127.5f;
  const float az = Cz * S, bz = Kz * S + 127.5f;
  // ix(p) = ix0 + p*dix with d = D0 + p*DSTEP
  const float ix0 = ax * D0 + bx, dix = ax * DSTEP;
  const float iy0 = ay * D0 + by, diy = ay * DSTEP;
  const float iz0 = az * D0 + bz, diz = az * DSTEP;

  // --- slab intervals in p-space -------------------------------------------
  float plo_in = -1e9f, phi_in = 1e9f, plo_out = -1e9f, phi_out = 1e9f;
  auto slab = [](float a, float b, float L, float H, float& lo, float& hi) {
    if (fabsf(a) < 1e-5f) {           // drift over 320 steps < 0.0032 < margin
      if (b < L || b > H) { lo = 1e9f; hi = -1e9f; }
    } else {
      const float p1 = (L - b) / a, p2 = (H - b) / a;
      lo = fmaxf(lo, fminf(p1, p2));
      hi = fminf(hi, fmaxf(p1, p2));
    }
  };
  slab(dix, ix0, 0.01f, 254.99f, plo_in, phi_in);
  slab(diy, iy0, 0.01f, 254.99f, plo_in, phi_in);
  slab(diz, iz0, 0.01f, 254.99f, plo_in, phi_in);
  slab(dix, ix0, -1.01f, 256.01f, plo_out, phi_out);
  slab(diy, iy0, -1.01f, 256.01f, plo_out, phi_out);
  slab(diz, iz0, -1.01f, 256.01f, plo_out, phi_out);

  const int i_in_lo  = (int)ceilf(fminf(fmaxf(plo_in, 0.0f), 320.0f));
  const int i_in_hi  = (int)floorf(fminf(fmaxf(phi_in, -1.0f), 319.0f)) + 1;
  const int i_out_lo = (int)ceilf(fminf(fmaxf(plo_out, 0.0f), 320.0f));
  const int i_out_hi = (int)floorf(fminf(fmaxf(phi_out, -1.0f), 319.0f)) + 1;

  float acc = 0.0f;   // chunk-local composited rgb
  float Tac = 1.0f;   // chunk-local transmittance
  const int p0 = chunk * CHUNK;

  // Transmittance bound: upstream interior steps (each multiplies T by 0.9
  // exactly; boundary steps only shrink T further).
  const int u_int = min(p0, i_in_hi) - i_in_lo;
  if (u_int < SKIP_STEPS) {

    // exact (clamped + masked) sample
    auto masked_sample = [&](int p) {
      const float pf = (float)p;
      const float ix = fmaf(pf, dix, ix0);
      const float iy = fmaf(pf, diy, iy0);
      const float iz = fmaf(pf, diz, iz0);
      if (ix > -1.0f && ix < 256.0f && iy > -1.0f && iy < 256.0f &&
          iz > -1.0f && iz < 256.0f) {
        const float xf = floorf(ix), yf = floorf(iy), zf = floorf(iz);
        const float fx = ix - xf, fy = iy - yf, fz = iz - zf;
        const int x0 = (int)xf, y0 = (int)yf, z0 = (int)zf;
        const float wx0 = (x0 >= 0)   ? 1.0f - fx : 0.0f;
        const float wx1 = (x0 <= 254) ? fx        : 0.0f;
        const float wy0 = (y0 >= 0)   ? 1.0f - fy : 0.0f;
        const float wy1 = (y0 <= 254) ? fy        : 0.0f;
        const float wz0 = (z0 >= 0)   ? 1.0f - fz : 0.0f;
        const float wz1 = (z0 <= 254) ? fz        : 0.0f;
        const int xc0 = max(x0, 0),     xc1 = min(x0 + 1, 255);
        const int yc0 = max(y0, 0),     yc1 = min(y0 + 1, 255);
        const int zc0 = max(z0, 0),     zc1 = min(z0 + 1, 255);
        const int b00 = (zc0 * 256 + yc0) * 256;
        const int b01 = (zc0 * 256 + yc1) * 256;
        const int b10 = (zc1 * 256 + yc0) * 256;
        const int b11 = (zc1 * 256 + yc1) * 256;
        const float v000 = vol[b00 + xc0], v001 = vol[b00 + xc1];
        const float v010 = vol[b01 + xc0], v011 = vol[b01 + xc1];
        const float v100 = vol[b10 + xc0], v101 = vol[b10 + xc1];
        const float v110 = vol[b11 + xc0], v111 = vol[b11 + xc1];
        const float fs =
            wz0 * (wy0 * (wx0 * v000 + wx1 * v001) +
                   wy1 * (wx0 * v010 + wx1 * v011)) +
            wz1 * (wy0 * (wx0 * v100 + wx1 * v101) +
                   wy1 * (wx0 * v110 + wx1 * v111));
        const float wsum  = (wx0 + wx1) * (wy0 + wy1) * (wz0 + wz1);
        const float sigma = DENSITY_C * wsum;
        acc = fmaf(sigma * Tac, fs, acc);
        Tac *= (1.0f + 1e-10f - sigma);
      } else {
        Tac *= (1.0f + 1e-10f);
      }
    };

    // single interior trilinear sample (remainder loop)
    auto fast_sample = [&](int p) -> float {
      const float pf = (float)p;
      const float ix = fmaf(pf, dix, ix0);
      const float iy = fmaf(pf, diy, iy0);
      const float iz = fmaf(pf, diz, iz0);
      const int x0 = (int)ix, y0 = (int)iy, z0 = (int)iz;
      const float fx = ix - (float)x0;
      const float fy = iy - (float)y0;
      const float fz = iz - (float)z0;
      const int base = (z0 << 16) + (y0 << 8) + x0;
      const float* b0 = vol + base;
      const float* b1 = vol + base + 65536;
      const float2 va = *reinterpret_cast<const float2*>(b0);
      const float2 vb = *reinterpret_cast<const float2*>(b0 + 256);
      const float2 vc = *reinterpret_cast<const float2*>(b1);
      const float2 vd = *reinterpret_cast<const float2*>(b1 + 256);
      const float c00 = fmaf(fx, va.y - va.x, va.x);
      const float c01 = fmaf(fx, vb.y - vb.x, vb.x);
      const float c10 = fmaf(fx, vc.y - vc.x, vc.x);
      const float c11 = fmaf(fx, vd.y - vd.x, vd.x);
      const float c0  = fmaf(fy, c01 - c00, c00);
      const float c1  = fmaf(fy, c11 - c10, c10);
      return fmaf(fz, c1 - c0, c0);
    };

    // partition [lo_o, hi_o) into masked | fast | masked
    const int lo_o = max(p0, i_out_lo);
    const int hi_o = min(p0 + CHUNK, i_out_hi);
    const int lo_f = min(max(lo_o, i_in_lo), hi_o);
    const int hi_f = min(max(lo_f, i_in_hi), hi_o);

    for (int p = lo_o; p < lo_f; ++p) masked_sample(p);

    // groups of 8: 32 independent float2 loads in flight per wait.
    int p = lo_f;
#pragma unroll 1
    for (; p + 8 <= hi_f; p += 8) {
      float2 va[8], vb[8], vc[8], vd[8];
      float fx[8], fy[8], fz[8];
#pragma unroll
      for (int k = 0; k < 8; ++k) {
        const float pf = (float)(p + k);
        const float ix = fmaf(pf, dix, ix0);
        const float iy = fmaf(pf, diy, iy0);
        const float iz = fmaf(pf, diz, iz0);
        const int x0 = (int)ix, y0 = (int)iy, z0 = (int)iz;  // trunc==floor
        fx[k] = ix - (float)x0;
        fy[k] = iy - (float)y0;
        fz[k] = iz - (float)z0;
        const int base = (z0 << 16) + (y0 << 8) + x0;
        const float* b0 = vol + base;
        const float* b1 = vol + base + 65536;
        va[k] = *reinterpret_cast<const float2*>(b0);
        vb[k] = *reinterpret_cast<const float2*>(b0 + 256);
        vc[k] = *reinterpret_cast<const float2*>(b1);
        vd[k] = *reinterpret_cast<const float2*>(b1 + 256);
      }
      const float W8[8] = {1.0f, 0.9f, 0.81f, 0.729f,
                           0.6561f, 0.59049f, 0.531441f, 0.4782969f};
      float g = 0.0f;
#pragma unroll
      for (int k = 0; k < 8; ++k) {
        const float c00 = fmaf(fx[k], va[k].y - va[k].x, va[k].x);
        const float c01 = fmaf(fx[k], vb[k].y - vb[k].x, vb[k].x);
        const float c10 = fmaf(fx[k], vc[k].y - vc[k].x, vc[k].x);
        const float c11 = fmaf(fx[k], vd[k].y - vd[k].x, vd[k].x);
        const float c0  = fmaf(fy[k], c01 - c00, c00);
        const float c1  = fmaf(fy[k], c11 - c10, c10);
        const float fs  = fmaf(fz[k], c1 - c0, c0);
        g = fmaf(W8[k], fs, g);
      }
      acc = fmaf(Tac * DENSITY_C, g, acc);
      Tac *= 0.43046721f;   // 0.9^8
    }
    for (; p < hi_f; ++p) {
      const float fs = fast_sample(p);
      acc = fmaf(Tac * DENSITY_C, fs, acc);
      Tac *= (1.0f - DENSITY_C);
    }

    for (p = hi_f; p < hi_o; ++p) masked_sample(p);
  }  // else: skipped chunk, acc = 0, Tac = 1 (error < 1e-6 in raw)

  __shared__ float lrgb[NCHUNK][PIX_PER_BLOCK];
  __shared__ float lT[NCHUNK][PIX_PER_BLOCK];
  lrgb[chunk][lane] = acc;
  lT[chunk][lane]   = Tac;
  __syncthreads();

  if (threadIdx.x < 64) {
    float a = 0.0f, Tp = 1.0f;
#pragma unroll
    for (int c = 0; c < NCHUNK; ++c) {
      a  = fmaf(Tp, lrgb[c][lane], a);
      Tp *= lT[c][lane];
    }
    raw[pixel] = a;

    float s = a, q = a * a, mn = a, mx = a;
#pragma unroll
    for (int off = 32; off > 0; off >>= 1) {
      s += __shfl_down(s, off, 64);
      q += __shfl_down(q, off, 64);
      mn = fminf(mn, __shfl_down(mn, off, 64));
      mx = fmaxf(mx, __shfl_down(mx, off, 64));
    }
    if (lane == 0) {
      bsum[blockIdx.x]   = s;
      bsumsq[blockIdx.x] = q;
      bmin[blockIdx.x]   = mn;
      bmax[blockIdx.x]   = mx;
    }
  }
}

// ---------------------------------------------------------------------------
// Kernel 2 (ROUND-7 REWRITE): fused stats + normalize + transpose.
//   Old: 64 blocks x 1024 thr, 24KB LDS of doubles, 11 __syncthreads,
//   64x-redundant 1024-elem tree, and a fully-scattered stride-1KB
//   transpose read (64 lines per wave-load, cross-XCD dirty lines).
//   New: 64 blocks x 256 thr. Stats: float4 loads + double accumulate +
//   wave shuffle-reduce + 4-entry LDS combine (1 barrier). Transpose:
//   32x32 LDS tile (pad [32][33]) -> coalesced read AND coalesced write.
// ---------------------------------------------------------------------------
__global__ __launch_bounds__(256)
void finalize_kernel(const float* __restrict__ raw,
                     const float* __restrict__ bsum,
                     const float* __restrict__ bsumsq,
                     const float* __restrict__ bmin,
                     const float* __restrict__ bmax,
                     float* __restrict__ out) {
  __shared__ double LS[4], LQ[4];
  __shared__ float  LMn[4], LMx[4];
  __shared__ float  tile[32][33];

  const int t    = threadIdx.x;
  const int lane = t & 63;
  const int wid  = t >> 6;

  // ---- stats: 1024 partials per array, 4 per thread via float4 ------------
  const float4 vs = reinterpret_cast<const float4*>(bsum)[t];
  const float4 vq = reinterpret_cast<const float4*>(bsumsq)[t];
  const float4 vn = reinterpret_cast<const float4*>(bmin)[t];
  const float4 vx = reinterpret_cast<const float4*>(bmax)[t];
  double ds = (double)vs.x + (double)vs.y + (double)vs.z + (double)vs.w;
  double dq = (double)vq.x + (double)vq.y + (double)vq.z + (double)vq.w;
  float  mn = fminf(fminf(vn.x, vn.y), fminf(vn.z, vn.w));
  float  mx = fmaxf(fmaxf(vx.x, vx.y), fmaxf(vx.z, vx.w));
#pragma unroll
  for (int off = 32; off > 0; off >>= 1) {
    ds += __shfl_down(ds, off, 64);
    dq += __shfl_down(dq, off, 64);
    mn = fminf(mn, __shfl_down(mn, off, 64));
    mx = fmaxf(mx, __shfl_down(mx, off, 64));
  }
  if (lane == 0) { LS[wid] = ds; LQ[wid] = dq; LMn[wid] = mn; LMx[wid] = mx; }
  __syncthreads();

  const double sum   = LS[0] + LS[1] + LS[2] + LS[3];
  const double sumsq = LQ[0] + LQ[1] + LQ[2] + LQ[3];
  const float  gmn   = fminf(fminf(LMn[0], LMn[1]), fminf(LMn[2], LMn[3]));
  const float  gmx   = fmaxf(fmaxf(LMx[0], LMx[1]), fmaxf(LMx[2], LMx[3]));

  const double N = 65536.0;
  const double mean = sum / N;
  double var = (sumsq - sum * sum / N) / (N - 1.0);
  if (var < 0.0) var = 0.0;
  const float stdeps = (float)sqrt(var) + 1e-8f;
  const float inv_std = 1.0f / stdeps;
  const float fmean = (float)mean;
  const float smin = (gmn - fmean) * inv_std;
  const float smax = (gmx - fmean) * inv_std;
  const float inv_range = 1.0f / (smax - smin + 1e-8f);

  // ---- 32x32 tile transpose: out[wq*256+hq] = norm(raw[hq*256+wq]) --------
  // block b: tileH = b&7 (raw row block), tileW = b>>3 (raw col block)
  const int H0 = (blockIdx.x & 7) * 32;
  const int W0 = (blockIdx.x >> 3) * 32;
  const int tx = t & 31;       // fast index
  const int ty = t >> 5;       // 0..7

#pragma unroll
  for (int i = 0; i < 4; ++i) {
    const int r = ty + i * 8;  // 0..31
    tile[r][tx] = raw[(H0 + r) * 256 + (W0 + tx)];   // coalesced read
  }
  __syncthreads();
#pragma unroll
  for (int i = 0; i < 4; ++i) {
    const int r = ty + i * 8;  // 0..31
    const float s = (tile[tx][r] - fmean) * inv_std; // [32][33]: conflict-free
    out[(W0 + r) * 256 + (H0 + tx)] = (s - smin + 1e-8f) * inv_range;  // coalesced
  }
}

extern "C" void kernel_launch(void* const* d_in, const int* in_sizes, int n_in,
                              void* d_out, int out_size, void* d_ws, size_t ws_size,
                              hipStream_t stream) {
  const float* vol = (const float*)d_in[0];  // (256,256,256) fp32
  const float* R   = (const float*)d_in[1];  // (1,3,3)
  const float* T   = (const float*)d_in[2];  // (1,3)
  float* out = (float*)d_out;                // 65536 fp32

  float* raw    = (float*)d_ws;              // 65536
  float* bsum   = raw + 65536;               // 1024
  float* bsumsq = bsum + 1024;               // 1024
  float* bmin   = bsumsq + 1024;             // 1024
  float* bmax   = bmin + 1024;               // 1024

  render_kernel<<<1024, 512, 0, stream>>>(vol, R, T, raw, bsum, bsumsq, bmin, bmax);
  finalize_kernel<<<64, 256, 0, stream>>>(raw, bsum, bsumsq, bmin, bmax, out);
}

// Round 8
// 114.839 us; speedup vs baseline: 1.3683x; 1.0373x over previous
//
#include <hip/hip_runtime.h>

#define NPTS 320
#define NCHUNK 8
#define PIX_PER_BLOCK 64
#define D0 2.0f
#define DSTEP (4.0f / 319.0f)
#define HALFV (765.0f / 512.0f)  // (3/256)*255*0.5
#define DENSITY_C 0.1f
// 0.9^132 = 9.4e-7: contribution of any sample with >=132 upstream interior
// steps is < 1e-6 in raw (feat<=1, sum(weights) <= T_upstream).
#define SKIP_STEPS 132

// ---------------------------------------------------------------------------
// Kernel 1: ray-march. Block = 512 threads = 8 waves. lane (0..63) = pixel,
// wave (0..7) = depth SEGMENT. ROUND-8 CHANGE: wave-uniform balanced split.
//   Fixed 40-sample chunks made every block's critical path ~40 samples
//   regardless of its total work (skip cut traffic, not the longest chain).
//   All 8 waves see the SAME 64 pixels, so each wave computes the block's
//   active-range union [blo,bhi) by a 6-step __shfl_xor min/max reduce and
//   takes the wave-uniform slice [blo+n*w/8, blo+n*(w+1)/8). Lane-to-lane
//   depth spread stays small (unlike R4's per-lane split: 3x lines/gather).
//   Per-block critical path 40 -> n/8+boundary (~11-27). Chunk-granular
//   transmittance skip replaced by finer per-lane clamp
//   B = min(i_out_hi, i_in_lo + 132) (same <1e-6 error bound).
//   Segmented compositing: wave segments tile each lane's [A,B) exactly
//   (wave-uniform boundaries, per-lane intersection) -> combine unchanged.
// ---------------------------------------------------------------------------
__global__ __launch_bounds__(512, 4)
void render_kernel(const float* __restrict__ vol,
                   const float* __restrict__ R,
                   const float* __restrict__ T,
                   float* __restrict__ raw,
                   float* __restrict__ bsum,
                   float* __restrict__ bsumsq,
                   float* __restrict__ bmin,
                   float* __restrict__ bmax) {
  const int lane  = threadIdx.x & 63;
  const int wave  = threadIdx.x >> 6;
  const int pixel = blockIdx.x * PIX_PER_BLOCK + lane;
  const int h = pixel >> 8;
  const int w = pixel & 255;

  // camera-plane coords / FOCAL(=2)
  const float xh = (w * (2.0f / 255.0f) - 1.0f) * 0.5f;
  const float yh = (h * (2.0f / 255.0f) - 1.0f) * 0.5f;

  const float R00 = R[0], R01 = R[1], R02 = R[2];
  const float R10 = R[3], R11 = R[4], R12 = R[5];
  const float R20 = R[6], R21 = R[7], R22 = R[8];
  const float T0 = T[0], T1 = T[1], T2 = T[2];

  // pw = R * (pcam - T); pcam = (xh*d, yh*d, d) -> voxel coords LINEAR in d.
  const float S = 127.5f / HALFV;
  const float Cx = R00 * xh + R01 * yh + R02;
  const float Cy = R10 * xh + R11 * yh + R12;
  const float Cz = R20 * xh + R21 * yh + R22;
  const float Kx = -(R00 * T0 + R01 * T1 + R02 * T2);
  const float Ky = -(R10 * T0 + R11 * T1 + R12 * T2);
  const float Kz = -(R20 * T0 + R21 * T1 + R22 * T2);
  const float ax = Cx * S, bx = Kx * S + 127.5f;
  const float ay = Cy * S, by = Ky * S + 127.5f;
  const float az = Cz * S, bz = Kz * S + 127.5f;
  // ix(p) = ix0 + p*dix with d = D0 + p*DSTEP
  const float ix0 = ax * D0 + bx, dix = ax * DSTEP;
  const float iy0 = ay * D0 + by, diy = ay * DSTEP;
  const float iz0 = az * D0 + bz, diz = az * DSTEP;

  // --- slab intervals in p-space -------------------------------------------
  float plo_in = -1e9f, phi_in = 1e9f, plo_out = -1e9f, phi_out = 1e9f;
  auto slab = [](float a, float b, float L, float H, float& lo, float& hi) {
    if (fabsf(a) < 1e-5f) {           // drift over 320 steps < 0.0032 < margin
      if (b < L || b > H) { lo = 1e9f; hi = -1e9f; }
    } else {
      const float p1 = (L - b) / a, p2 = (H - b) / a;
      lo = fmaxf(lo, fminf(p1, p2));
      hi = fminf(hi, fmaxf(p1, p2));
    }
  };
  slab(dix, ix0, 0.01f, 254.99f, plo_in, phi_in);
  slab(diy, iy0, 0.01f, 254.99f, plo_in, phi_in);
  slab(diz, iz0, 0.01f, 254.99f, plo_in, phi_in);
  slab(dix, ix0, -1.01f, 256.01f, plo_out, phi_out);
  slab(diy, iy0, -1.01f, 256.01f, plo_out, phi_out);
  slab(diz, iz0, -1.01f, 256.01f, plo_out, phi_out);

  const int i_in_lo  = (int)ceilf(fminf(fmaxf(plo_in, 0.0f), 320.0f));
  const int i_in_hi  = (int)floorf(fminf(fmaxf(phi_in, -1.0f), 319.0f)) + 1;
  const int i_out_lo = (int)ceilf(fminf(fmaxf(plo_out, 0.0f), 320.0f));
  const int i_out_hi = (int)floorf(fminf(fmaxf(phi_out, -1.0f), 319.0f)) + 1;

  // ---- per-lane active range with fine transmittance clamp ----------------
  const int A0 = i_out_lo;
  int B0 = i_out_hi;
  if (i_in_hi - i_in_lo >= SKIP_STEPS) B0 = min(B0, i_in_lo + SKIP_STEPS);
  const bool empty = (A0 >= B0);

  // ---- block-uniform union via wave reduce (all waves see same 64 pixels) -
  int rlo = empty ? (1 << 20) : A0;
  int rhi = empty ? -(1 << 20) : B0;
#pragma unroll
  for (int off = 32; off > 0; off >>= 1) {
    rlo = min(rlo, __shfl_xor(rlo, off, 64));
    rhi = max(rhi, __shfl_xor(rhi, off, 64));
  }
  const int n = max(0, rhi - rlo);
  // wave-uniform segment bounds (n <= 321: no overflow)
  const int seg_lo = rlo + ((n * wave) >> 3);
  const int seg_hi = rlo + ((n * (wave + 1)) >> 3);

  // per-lane bounds within this wave's segment
  const int lo_o = empty ? 0 : max(seg_lo, A0);
  const int hi_o = empty ? 0 : min(seg_hi, B0);

  float acc = 0.0f;   // segment-local composited rgb
  float Tac = 1.0f;   // segment-local transmittance

  // exact (clamped + masked) sample
  auto masked_sample = [&](int p) {
    const float pf = (float)p;
    const float ix = fmaf(pf, dix, ix0);
    const float iy = fmaf(pf, diy, iy0);
    const float iz = fmaf(pf, diz, iz0);
    if (ix > -1.0f && ix < 256.0f && iy > -1.0f && iy < 256.0f &&
        iz > -1.0f && iz < 256.0f) {
      const float xf = floorf(ix), yf = floorf(iy), zf = floorf(iz);
      const float fx = ix - xf, fy = iy - yf, fz = iz - zf;
      const int x0 = (int)xf, y0 = (int)yf, z0 = (int)zf;
      const float wx0 = (x0 >= 0)   ? 1.0f - fx : 0.0f;
      const float wx1 = (x0 <= 254) ? fx        : 0.0f;
      const float wy0 = (y0 >= 0)   ? 1.0f - fy : 0.0f;
      const float wy1 = (y0 <= 254) ? fy        : 0.0f;
      const float wz0 = (z0 >= 0)   ? 1.0f - fz : 0.0f;
      const float wz1 = (z0 <= 254) ? fz        : 0.0f;
      const int xc0 = max(x0, 0),     xc1 = min(x0 + 1, 255);
      const int yc0 = max(y0, 0),     yc1 = min(y0 + 1, 255);
      const int zc0 = max(z0, 0),     zc1 = min(z0 + 1, 255);
      const int b00 = (zc0 * 256 + yc0) * 256;
      const int b01 = (zc0 * 256 + yc1) * 256;
      const int b10 = (zc1 * 256 + yc0) * 256;
      const int b11 = (zc1 * 256 + yc1) * 256;
      const float v000 = vol[b00 + xc0], v001 = vol[b00 + xc1];
      const float v010 = vol[b01 + xc0], v011 = vol[b01 + xc1];
      const float v100 = vol[b10 + xc0], v101 = vol[b10 + xc1];
      const float v110 = vol[b11 + xc0], v111 = vol[b11 + xc1];
      const float fs =
          wz0 * (wy0 * (wx0 * v000 + wx1 * v001) +
                 wy1 * (wx0 * v010 + wx1 * v011)) +
          wz1 * (wy0 * (wx0 * v100 + wx1 * v101) +
                 wy1 * (wx0 * v110 + wx1 * v111));
      const float wsum  = (wx0 + wx1) * (wy0 + wy1) * (wz0 + wz1);
      const float sigma = DENSITY_C * wsum;
      acc = fmaf(sigma * Tac, fs, acc);
      Tac *= (1.0f + 1e-10f - sigma);
    } else {
      Tac *= (1.0f + 1e-10f);
    }
  };

  // single interior trilinear sample (remainder loop)
  auto fast_sample = [&](int p) -> float {
    const float pf = (float)p;
    const float ix = fmaf(pf, dix, ix0);
    const float iy = fmaf(pf, diy, iy0);
    const float iz = fmaf(pf, diz, iz0);
    const int x0 = (int)ix, y0 = (int)iy, z0 = (int)iz;
    const float fx = ix - (float)x0;
    const float fy = iy - (float)y0;
    const float fz = iz - (float)z0;
    const int base = (z0 << 16) + (y0 << 8) + x0;
    const float* b0 = vol + base;
    const float* b1 = vol + base + 65536;
    const float2 va = *reinterpret_cast<const float2*>(b0);
    const float2 vb = *reinterpret_cast<const float2*>(b0 + 256);
    const float2 vc = *reinterpret_cast<const float2*>(b1);
    const float2 vd = *reinterpret_cast<const float2*>(b1 + 256);
    const float c00 = fmaf(fx, va.y - va.x, va.x);
    const float c01 = fmaf(fx, vb.y - vb.x, vb.x);
    const float c10 = fmaf(fx, vc.y - vc.x, vc.x);
    const float c11 = fmaf(fx, vd.y - vd.x, vd.x);
    const float c0  = fmaf(fy, c01 - c00, c00);
    const float c1  = fmaf(fy, c11 - c10, c10);
    return fmaf(fz, c1 - c0, c0);
  };

  // partition [lo_o, hi_o) into masked | fast | masked (per-lane bounds)
  const int lo_f = min(max(lo_o, i_in_lo), hi_o);
  const int hi_f = min(max(lo_f, i_in_hi), hi_o);

  for (int p = lo_o; p < lo_f; ++p) masked_sample(p);

  // groups of 8: 32 independent float2 loads in flight per wait.
  int p = lo_f;
#pragma unroll 1
  for (; p + 8 <= hi_f; p += 8) {
    float2 va[8], vb[8], vc[8], vd[8];
    float fx[8], fy[8], fz[8];
#pragma unroll
    for (int k = 0; k < 8; ++k) {
      const float pf = (float)(p + k);
      const float ix = fmaf(pf, dix, ix0);
      const float iy = fmaf(pf, diy, iy0);
      const float iz = fmaf(pf, diz, iz0);
      const int x0 = (int)ix, y0 = (int)iy, z0 = (int)iz;  // trunc==floor
      fx[k] = ix - (float)x0;
      fy[k] = iy - (float)y0;
      fz[k] = iz - (float)z0;
      const int base = (z0 << 16) + (y0 << 8) + x0;
      const float* b0 = vol + base;
      const float* b1 = vol + base + 65536;
      va[k] = *reinterpret_cast<const float2*>(b0);
      vb[k] = *reinterpret_cast<const float2*>(b0 + 256);
      vc[k] = *reinterpret_cast<const float2*>(b1);
      vd[k] = *reinterpret_cast<const float2*>(b1 + 256);
    }
    const float W8[8] = {1.0f, 0.9f, 0.81f, 0.729f,
                         0.6561f, 0.59049f, 0.531441f, 0.4782969f};
    float g = 0.0f;
#pragma unroll
    for (int k = 0; k < 8; ++k) {
      const float c00 = fmaf(fx[k], va[k].y - va[k].x, va[k].x);
      const float c01 = fmaf(fx[k], vb[k].y - vb[k].x, vb[k].x);
      const float c10 = fmaf(fx[k], vc[k].y - vc[k].x, vc[k].x);
      const float c11 = fmaf(fx[k], vd[k].y - vd[k].x, vd[k].x);
      const float c0  = fmaf(fy[k], c01 - c00, c00);
      const float c1  = fmaf(fy[k], c11 - c10, c10);
      const float fs  = fmaf(fz[k], c1 - c0, c0);
      g = fmaf(W8[k], fs, g);
    }
    acc = fmaf(Tac * DENSITY_C, g, acc);
    Tac *= 0.43046721f;   // 0.9^8
  }
  for (; p < hi_f; ++p) {
    const float fs = fast_sample(p);
    acc = fmaf(Tac * DENSITY_C, fs, acc);
    Tac *= (1.0f - DENSITY_C);
  }

  for (p = hi_f; p < hi_o; ++p) masked_sample(p);

  __shared__ float lrgb[NCHUNK][PIX_PER_BLOCK];
  __shared__ float lT[NCHUNK][PIX_PER_BLOCK];
  lrgb[wave][lane] = acc;
  lT[wave][lane]   = Tac;
  __syncthreads();

  if (threadIdx.x < 64) {
    float a = 0.0f, Tp = 1.0f;
#pragma unroll
    for (int c = 0; c < NCHUNK; ++c) {
      a  = fmaf(Tp, lrgb[c][lane], a);
      Tp *= lT[c][lane];
    }
    raw[pixel] = a;

    float s = a, q = a * a, mn = a, mx = a;
#pragma unroll
    for (int off = 32; off > 0; off >>= 1) {
      s += __shfl_down(s, off, 64);
      q += __shfl_down(q, off, 64);
      mn = fminf(mn, __shfl_down(mn, off, 64));
      mx = fmaxf(mx, __shfl_down(mx, off, 64));
    }
    if (lane == 0) {
      bsum[blockIdx.x]   = s;
      bsumsq[blockIdx.x] = q;
      bmin[blockIdx.x]   = mn;
      bmax[blockIdx.x]   = mx;
    }
  }
}

// ---------------------------------------------------------------------------
// Kernel 2: fused stats + normalize + transpose (round-7 version, ~2-3 us).
// ---------------------------------------------------------------------------
__global__ __launch_bounds__(256)
void finalize_kernel(const float* __restrict__ raw,
                     const float* __restrict__ bsum,
                     const float* __restrict__ bsumsq,
                     const float* __restrict__ bmin,
                     const float* __restrict__ bmax,
                     float* __restrict__ out) {
  __shared__ double LS[4], LQ[4];
  __shared__ float  LMn[4], LMx[4];
  __shared__ float  tile[32][33];

  const int t    = threadIdx.x;
  const int lane = t & 63;
  const int wid  = t >> 6;

  // ---- stats: 1024 partials per array, 4 per thread via float4 ------------
  const float4 vs = reinterpret_cast<const float4*>(bsum)[t];
  const float4 vq = reinterpret_cast<const float4*>(bsumsq)[t];
  const float4 vn = reinterpret_cast<const float4*>(bmin)[t];
  const float4 vx = reinterpret_cast<const float4*>(bmax)[t];
  double ds = (double)vs.x + (double)vs.y + (double)vs.z + (double)vs.w;
  double dq = (double)vq.x + (double)vq.y + (double)vq.z + (double)vq.w;
  float  mn = fminf(fminf(vn.x, vn.y), fminf(vn.z, vn.w));
  float  mx = fmaxf(fmaxf(vx.x, vx.y), fmaxf(vx.z, vx.w));
#pragma unroll
  for (int off = 32; off > 0; off >>= 1) {
    ds += __shfl_down(ds, off, 64);
    dq += __shfl_down(dq, off, 64);
    mn = fminf(mn, __shfl_down(mn, off, 64));
    mx = fmaxf(mx, __shfl_down(mx, off, 64));
  }
  if (lane == 0) { LS[wid] = ds; LQ[wid] = dq; LMn[wid] = mn; LMx[wid] = mx; }
  __syncthreads();

  const double sum   = LS[0] + LS[1] + LS[2] + LS[3];
  const double sumsq = LQ[0] + LQ[1] + LQ[2] + LQ[3];
  const float  gmn   = fminf(fminf(LMn[0], LMn[1]), fminf(LMn[2], LMn[3]));
  const float  gmx   = fmaxf(fmaxf(LMx[0], LMx[1]), fmaxf(LMx[2], LMx[3]));

  const double N = 65536.0;
  const double mean = sum / N;
  double var = (sumsq - sum * sum / N) / (N - 1.0);
  if (var < 0.0) var = 0.0;
  const float stdeps = (float)sqrt(var) + 1e-8f;
  const float inv_std = 1.0f / stdeps;
  const float fmean = (float)mean;
  const float smin = (gmn - fmean) * inv_std;
  const float smax = (gmx - fmean) * inv_std;
  const float inv_range = 1.0f / (smax - smin + 1e-8f);

  // ---- 32x32 tile transpose: out[wq*256+hq] = norm(raw[hq*256+wq]) --------
  const int H0 = (blockIdx.x & 7) * 32;
  const int W0 = (blockIdx.x >> 3) * 32;
  const int tx = t & 31;
  const int ty = t >> 5;

#pragma unroll
  for (int i = 0; i < 4; ++i) {
    const int r = ty + i * 8;
    tile[r][tx] = raw[(H0 + r) * 256 + (W0 + tx)];   // coalesced read
  }
  __syncthreads();
#pragma unroll
  for (int i = 0; i < 4; ++i) {
    const int r = ty + i * 8;
    const float s = (tile[tx][r] - fmean) * inv_std; // [32][33]: conflict-free
    out[(W0 + r) * 256 + (H0 + tx)] = (s - smin + 1e-8f) * inv_range;  // coalesced
  }
}

extern "C" void kernel_launch(void* const* d_in, const int* in_sizes, int n_in,
                              void* d_out, int out_size, void* d_ws, size_t ws_size,
                              hipStream_t stream) {
  const float* vol = (const float*)d_in[0];  // (256,256,256) fp32
  const float* R   = (const float*)d_in[1];  // (1,3,3)
  const float* T   = (const float*)d_in[2];  // (1,3)
  float* out = (float*)d_out;                // 65536 fp32

  float* raw    = (float*)d_ws;              // 65536
  float* bsum   = raw + 65536;               // 1024
  float* bsumsq = bsum + 1024;               // 1024
  float* bmin   = bsumsq + 1024;             // 1024
  float* bmax   = bmin + 1024;               // 1024

  render_kernel<<<1024, 512, 0, stream>>>(vol, R, T, raw, bsum, bsumsq, bmin, bmax);
  finalize_kernel<<<64, 256, 0, stream>>>(raw, bsum, bsumsq, bmin, bmax, out);
}